// Round 1
// baseline (1232.299 us; speedup 1.0000x reference)
//
#include <hip/hip_runtime.h>
#include <hip/hip_bf16.h>

#define NN 64
#define CC 128
#define TT 300
#define VV 25
#define TV 7500
#define DD 256
#define RR 32

// workspace float offsets
#define OFF_SUM1   0
#define OFF_SUMSQ1 128
#define OFF_A1     256
#define OFF_B1     384
#define OFF_SUM2   512
#define OFF_SUMSQ2 768
#define OFF_A2     1024
#define OFF_B2     1280
#define OFF_P      1536          // 64*128 = 8192
#define OFF_GATE   9728          // 64*4 = 256
#define OFF_BBUF   9984          // 64*256 = 16384
#define OFF_WBUF   26368         // 64*128*256 = 2097152
#define Z_BYTE_OFF ((size_t)(26368 + 2097152) * 4)   // 8,494,080 bytes; z = 122.88M bf16

__device__ inline void block_reduce2(float& a, float& b) {
    __shared__ float sa[4], sb[4];
    for (int off = 32; off > 0; off >>= 1) {
        a += __shfl_down(a, off);
        b += __shfl_down(b, off);
    }
    int lane = threadIdx.x & 63, wid = threadIdx.x >> 6;
    if (lane == 0) { sa[wid] = a; sb[wid] = b; }
    __syncthreads();
    if (threadIdx.x == 0) {
        a = sa[0] + sa[1] + sa[2] + sa[3];
        b = sb[0] + sb[1] + sb[2] + sb[3];
    }
}

__global__ void k_zero(float* ws) {
    int i = threadIdx.x;
    for (; i < 1536; i += 256) ws[i] = 0.f;
}

// per-channel sum/sumsq of x over (N,T,V). grid: 2048 = 128c * 16 groups
__global__ __launch_bounds__(256) void k_bn1_stats(const float* __restrict__ x, float* __restrict__ ws) {
    int c = blockIdx.x & 127;
    int g = blockIdx.x >> 7;
    float s = 0.f, ss = 0.f;
    for (int nn = 0; nn < 4; ++nn) {
        int n = g * 4 + nn;
        const float4* row = (const float4*)(x + (size_t)(n * CC + c) * TV);
        for (int i = threadIdx.x; i < TV / 4; i += 256) {
            float4 u = row[i];
            s  += u.x + u.y + u.z + u.w;
            ss += u.x * u.x + u.y * u.y + u.z * u.z + u.w * u.w;
        }
    }
    block_reduce2(s, ss);
    if (threadIdx.x == 0) {
        atomicAdd(&ws[OFF_SUM1 + c], s);
        atomicAdd(&ws[OFF_SUMSQ1 + c], ss);
    }
}

__global__ void k_bn1_final(const float* __restrict__ g1, const float* __restrict__ b1, float* ws) {
    int c = threadIdx.x;
    if (c < CC) {
        const float inv = 1.f / (float)(NN * TV);
        float m = ws[OFF_SUM1 + c] * inv;
        float var = ws[OFF_SUMSQ1 + c] * inv - m * m;
        float rstd = rsqrtf(var + 1e-5f);
        float A = rstd * g1[c];
        ws[OFF_A1 + c] = A;
        ws[OFF_B1 + c] = b1[c] - m * A;
    }
}

// fused: BN1-apply + temporal shift (in) + write y(bf16) + p[n,c] mean. grid 8192 = n*128+c
__global__ __launch_bounds__(256) void k_shift_y_p(const float* __restrict__ x,
                                                   const float* __restrict__ shift_in,
                                                   float* __restrict__ ws,
                                                   __hip_bfloat16* __restrict__ ybuf) {
    __shared__ float w0s[TT], w1s[TT];
    __shared__ int   i0s[TT], i1s[TT];
    int n = blockIdx.x >> 7, c = blockIdx.x & 127;
    float sh = shift_in[c];
    for (int t = threadIdx.x; t < TT; t += 256) {
        float pos = (float)t + sh;
        float f0 = floorf(pos);
        int i0 = (int)f0;
        float frac = pos - f0;
        int i1 = i0 + 1;
        w0s[t] = (i0 >= 0 && i0 < TT) ? (1.f - frac) : 0.f;
        w1s[t] = (i1 >= 0 && i1 < TT) ? frac : 0.f;
        i0s[t] = min(max(i0, 0), TT - 1);
        i1s[t] = min(max(i1, 0), TT - 1);
    }
    __syncthreads();
    const float* row = x + (size_t)(n * CC + c) * TV;
    float A = ws[OFF_A1 + c], B = ws[OFF_B1 + c];
    size_t obase = (size_t)(n * CC + c) * TV;
    float acc = 0.f, dummy = 0.f;
    for (int j = threadIdx.x; j < TV; j += 256) {
        int t = j / VV, v = j - t * VV;
        float x0 = row[i0s[t] * VV + v];
        float x1 = row[i1s[t] * VV + v];
        float yv = (w0s[t] * x0 + w1s[t] * x1) * A + (w0s[t] + w1s[t]) * B;
        acc += yv;
        ybuf[obase + j] = __float2bfloat16(yv);
    }
    __syncthreads();
    block_reduce2(acc, dummy);
    if (threadIdx.x == 0) ws[OFF_P + n * CC + c] = acc / (float)TV;
}

// fc1 -> relu -> fc2 -> softmax(logits/tao) -> gate.  one block of 256 threads.
__global__ void k_gate(const float* __restrict__ fc1_w, const float* __restrict__ fc1_b,
                       const float* __restrict__ fc2_w, const float* __restrict__ fc2_b,
                       const int* __restrict__ epoch_p, float* ws) {
    __shared__ float hsh[NN][RR];
    int n = threadIdx.x >> 2;
    int rq = threadIdx.x & 3;
    for (int r = rq * 8; r < rq * 8 + 8; ++r) {
        float acc = fc1_b[r];
        for (int c = 0; c < CC; ++c) acc += ws[OFF_P + n * CC + c] * fc1_w[r * CC + c];
        hsh[n][r] = fmaxf(acc, 0.f);
    }
    __syncthreads();
    if (threadIdx.x < NN) {
        int nn = threadIdx.x;
        int ep = *epoch_p;
        float tao = (ep < 60) ? (-(29.f / 60.f) * (float)ep + 30.f) : 1.f;
        float li[4];
        float mx = -1e30f;
        for (int k = 0; k < 4; ++k) {
            float acc = fc2_b[k];
            for (int r = 0; r < RR; ++r) acc += hsh[nn][r] * fc2_w[k * RR + r];
            li[k] = acc / tao;
            mx = fmaxf(mx, li[k]);
        }
        float se = 0.f;
        for (int k = 0; k < 4; ++k) { li[k] = expf(li[k] - mx); se += li[k]; }
        float inv = 1.f / se;
        for (int k = 0; k < 4; ++k) ws[OFF_GATE + nn * 4 + k] = li[k] * inv;
    }
}

// w[n,c,d] = sum_k gate[n,k]*tw[k,c,d].  grid 8192*256 = 2097152 threads
__global__ __launch_bounds__(256) void k_wmix(const float* __restrict__ tw, float* __restrict__ ws) {
    int idx = blockIdx.x * 256 + threadIdx.x;
    int n = idx >> 15;
    int cd = idx & 32767;
    const float* g = &ws[OFF_GATE + n * 4];
    float w = g[0] * tw[cd] + g[1] * tw[32768 + cd] + g[2] * tw[65536 + cd] + g[3] * tw[98304 + cd];
    ws[OFF_WBUF + idx] = w;
}

// b[n,d] = sum_k gate[n,k]*tb[k,d].  grid 64 blocks
__global__ void k_bmix(const float* __restrict__ tb, float* __restrict__ ws) {
    int n = blockIdx.x, d = threadIdx.x;
    const float* g = &ws[OFF_GATE + n * 4];
    ws[OFF_BBUF + n * DD + d] = g[0] * tb[d] + g[1] * tb[DD + d] + g[2] * tb[2 * DD + d] + g[3] * tb[3 * DD + d];
}

// z[n,d,tv] = relu( sum_c y[n,c,tv]*w[n,c,d] + b[n,d] ), bf16 out.
// grid (59 j-tiles, 4 d-tiles, 64 n); block 256: thread tile 4d x 8j.
__global__ __launch_bounds__(256) void k_gemm(const __hip_bfloat16* __restrict__ ybuf,
                                              const float* __restrict__ ws,
                                              __hip_bfloat16* __restrict__ zbuf) {
    __shared__ float ylds[16][128];
    __shared__ float wlds[16][64];
    int n = blockIdx.z;
    int dbase = blockIdx.y * 64;
    int j0 = blockIdx.x * 128;
    int jw = min(128, TV - j0);
    int dgrp = threadIdx.x >> 4;   // 0..15 -> d_local = dgrp*4
    int jgrp = threadIdx.x & 15;   // j_local = jgrp*8
    float acc[4][8];
#pragma unroll
    for (int a = 0; a < 4; ++a)
#pragma unroll
        for (int b = 0; b < 8; ++b) acc[a][b] = 0.f;

    const __hip_bfloat16* ybase = ybuf + (size_t)n * CC * TV;
    const float* wbase = ws + OFF_WBUF + (size_t)n * CC * DD;

    for (int ck = 0; ck < CC; ck += 16) {
        __syncthreads();
        for (int i = threadIdx.x; i < 16 * 128; i += 256) {
            int cc = i >> 7, jj = i & 127;
            float val = 0.f;
            if (jj < jw) val = __bfloat162float(ybase[(size_t)(ck + cc) * TV + j0 + jj]);
            ylds[cc][jj] = val;
        }
        for (int i = threadIdx.x; i < 16 * 64; i += 256) {
            int cc = i >> 6, dd = i & 63;
            wlds[cc][dd] = wbase[(ck + cc) * DD + dbase + dd];
        }
        __syncthreads();
#pragma unroll
        for (int cc = 0; cc < 16; ++cc) {
            float w4[4], y8[8];
            *(float4*)w4 = *(float4*)&wlds[cc][dgrp * 4];
            *(float4*)y8 = *(float4*)&ylds[cc][jgrp * 8];
            *(float4*)(y8 + 4) = *(float4*)&ylds[cc][jgrp * 8 + 4];
#pragma unroll
            for (int a = 0; a < 4; ++a)
#pragma unroll
                for (int b = 0; b < 8; ++b) acc[a][b] += w4[a] * y8[b];
        }
    }
#pragma unroll
    for (int a = 0; a < 4; ++a) {
        int d = dbase + dgrp * 4 + a;
        float bias = ws[OFF_BBUF + n * DD + d];
        size_t zrow = (size_t)(n * DD + d) * TV + j0 + jgrp * 8;
        int jb = j0 + jgrp * 8;
#pragma unroll
        for (int b = 0; b < 8; ++b) {
            if (jb + b < TV) {
                float r = fmaxf(acc[a][b] + bias, 0.f);
                zbuf[zrow + b] = __float2bfloat16(r);
            }
        }
    }
}

// per-d sum/sumsq of shifted z over (N,T,V).  grid 4096 = 256d * 16 groups
__global__ __launch_bounds__(256) void k_bn2_stats(const __hip_bfloat16* __restrict__ zbuf,
                                                   const float* __restrict__ shift_out,
                                                   float* __restrict__ ws) {
    __shared__ float w0s[TT], w1s[TT];
    __shared__ int   i0s[TT], i1s[TT];
    int d = blockIdx.x & 255;
    int g = blockIdx.x >> 8;
    float sh = shift_out[d];
    for (int t = threadIdx.x; t < TT; t += 256) {
        float pos = (float)t + sh;
        float f0 = floorf(pos);
        int i0 = (int)f0;
        float frac = pos - f0;
        int i1 = i0 + 1;
        w0s[t] = (i0 >= 0 && i0 < TT) ? (1.f - frac) : 0.f;
        w1s[t] = (i1 >= 0 && i1 < TT) ? frac : 0.f;
        i0s[t] = min(max(i0, 0), TT - 1);
        i1s[t] = min(max(i1, 0), TT - 1);
    }
    __syncthreads();
    float s = 0.f, ss = 0.f;
    for (int nn = 0; nn < 4; ++nn) {
        int n = g * 4 + nn;
        const __hip_bfloat16* zrow = zbuf + (size_t)(n * DD + d) * TV;
        for (int j = threadIdx.x; j < TV; j += 256) {
            int t = j / VV, v = j - t * VV;
            float z0 = __bfloat162float(zrow[i0s[t] * VV + v]);
            float z1 = __bfloat162float(zrow[i1s[t] * VV + v]);
            float sv = w0s[t] * z0 + w1s[t] * z1;
            s += sv;
            ss += sv * sv;
        }
    }
    __syncthreads();
    block_reduce2(s, ss);
    if (threadIdx.x == 0) {
        atomicAdd(&ws[OFF_SUM2 + d], s);
        atomicAdd(&ws[OFF_SUMSQ2 + d], ss);
    }
}

__global__ void k_bn2_final(const float* __restrict__ g2, const float* __restrict__ b2, float* ws) {
    int d = threadIdx.x;
    if (d < DD) {
        const float inv = 1.f / (float)(NN * TV);
        float m = ws[OFF_SUM2 + d] * inv;
        float var = ws[OFF_SUMSQ2 + d] * inv - m * m;
        float rstd = rsqrtf(var + 1e-5f);
        float A = rstd * g2[d];
        ws[OFF_A2 + d] = A;
        ws[OFF_B2 + d] = b2[d] - m * A;
    }
}

// out[n,d,tv] = shifted(z)*A2[d] + B2[d].  grid 16384 = n*256+d
__global__ __launch_bounds__(256) void k_out(const __hip_bfloat16* __restrict__ zbuf,
                                             const float* __restrict__ shift_out,
                                             const float* __restrict__ ws,
                                             float* __restrict__ out) {
    __shared__ float w0s[TT], w1s[TT];
    __shared__ int   i0s[TT], i1s[TT];
    int n = blockIdx.x >> 8, d = blockIdx.x & 255;
    float sh = shift_out[d];
    for (int t = threadIdx.x; t < TT; t += 256) {
        float pos = (float)t + sh;
        float f0 = floorf(pos);
        int i0 = (int)f0;
        float frac = pos - f0;
        int i1 = i0 + 1;
        w0s[t] = (i0 >= 0 && i0 < TT) ? (1.f - frac) : 0.f;
        w1s[t] = (i1 >= 0 && i1 < TT) ? frac : 0.f;
        i0s[t] = min(max(i0, 0), TT - 1);
        i1s[t] = min(max(i1, 0), TT - 1);
    }
    __syncthreads();
    float A = ws[OFF_A2 + d], B = ws[OFF_B2 + d];
    const __hip_bfloat16* zrow = zbuf + (size_t)(n * DD + d) * TV;
    float* orow = out + (size_t)(n * DD + d) * TV;
    for (int j = threadIdx.x; j < TV; j += 256) {
        int t = j / VV, v = j - t * VV;
        float z0 = __bfloat162float(zrow[i0s[t] * VV + v]);
        float z1 = __bfloat162float(zrow[i1s[t] * VV + v]);
        orow[j] = (w0s[t] * z0 + w1s[t] * z1) * A + B;
    }
}

extern "C" void kernel_launch(void* const* d_in, const int* in_sizes, int n_in,
                              void* d_out, int out_size, void* d_ws, size_t ws_size,
                              hipStream_t stream) {
    const float* x        = (const float*)d_in[0];
    const int*   epoch    = (const int*)d_in[1];
    const float* bn1_g    = (const float*)d_in[2];
    const float* bn1_b    = (const float*)d_in[3];
    const float* bn2_g    = (const float*)d_in[4];
    const float* bn2_b    = (const float*)d_in[5];
    const float* shift_in = (const float*)d_in[6];
    const float* shift_out= (const float*)d_in[7];
    const float* fc1_w    = (const float*)d_in[8];
    const float* fc1_b    = (const float*)d_in[9];
    const float* fc2_w    = (const float*)d_in[10];
    const float* fc2_b    = (const float*)d_in[11];
    const float* tw       = (const float*)d_in[12];
    const float* tb       = (const float*)d_in[13];
    float* out = (float*)d_out;
    float* ws  = (float*)d_ws;
    __hip_bfloat16* ybuf = (__hip_bfloat16*)d_out;  // y lives in d_out until k_out overwrites
    __hip_bfloat16* zbuf = (__hip_bfloat16*)((char*)d_ws + Z_BYTE_OFF);

    k_zero<<<1, 256, 0, stream>>>(ws);
    k_bn1_stats<<<2048, 256, 0, stream>>>(x, ws);
    k_bn1_final<<<1, 128, 0, stream>>>(bn1_g, bn1_b, ws);
    k_shift_y_p<<<8192, 256, 0, stream>>>(x, shift_in, ws, ybuf);
    k_gate<<<1, 256, 0, stream>>>(fc1_w, fc1_b, fc2_w, fc2_b, epoch, ws);
    k_wmix<<<8192, 256, 0, stream>>>(tw, ws);
    k_bmix<<<64, 256, 0, stream>>>(tb, ws);
    k_gemm<<<dim3(59, 4, 64), 256, 0, stream>>>(ybuf, ws, zbuf);
    k_bn2_stats<<<4096, 256, 0, stream>>>(zbuf, shift_out, ws);
    k_bn2_final<<<1, 256, 0, stream>>>(bn2_g, bn2_b, ws);
    k_out<<<16384, 256, 0, stream>>>(zbuf, shift_out, ws, out);
}

// Round 2
// 840.509 us; speedup vs baseline: 1.4661x; 1.4661x over previous
//
#include <hip/hip_runtime.h>
#include <stdint.h>

#define NN 64
#define CC 128
#define TT 300
#define VV 25
#define TV 7500
#define DD 256
#define RR 32
#define JPAD 7552   // 59 * 128 j-rows (padded)

// ws float offsets
#define OFF_SUM1   0
#define OFF_SUMSQ1 128
#define OFF_A1     256
#define OFF_B1     384
#define OFF_SUM2   512
#define OFF_SUMSQ2 768
#define OFF_A2     1024
#define OFF_B2     1280
#define OFF_P      1536          // 64*128 raw sums
#define OFF_GATE   9728          // 64*4
#define OFF_BBUF   9984          // 64*256
#define FLOAT_REGION 26368
#define WT_BYTE_OFF ((size_t)FLOAT_REGION * 4)          // 105472
#define WT_BYTES    ((size_t)NN * DD * CC * 2)          // 4 MB bf16 wT[n][d][c] (chunk-swizzled)
#define Z_BYTE_OFF  (WT_BYTE_OFF + WT_BYTES)            // z: 64*256*7500 bf16 = 245.76 MB

typedef __attribute__((ext_vector_type(8))) short short8;
typedef __attribute__((ext_vector_type(4))) float f32x4;

typedef const __attribute__((address_space(1))) uint32_t gas_u32;
typedef __attribute__((address_space(3))) uint32_t las_u32;

__device__ inline ushort f2bf(float f) {           // RNE f32 -> bf16 bits
    uint32_t u = __float_as_uint(f);
    u += 0x7fffu + ((u >> 16) & 1u);
    return (ushort)(u >> 16);
}
__device__ inline float bf2f(ushort v) {
    return __uint_as_float(((uint32_t)v) << 16);
}
__device__ inline void async_copy16(const void* g, void* l) {
    __builtin_amdgcn_global_load_lds((gas_u32*)g, (las_u32*)l, 16, 0, 0);
}

__device__ inline void block_reduce2(float& a, float& b) {
    __shared__ float sa[4], sb[4];
    for (int off = 32; off > 0; off >>= 1) {
        a += __shfl_down(a, off);
        b += __shfl_down(b, off);
    }
    int lane = threadIdx.x & 63, wid = threadIdx.x >> 6;
    if (lane == 0) { sa[wid] = a; sb[wid] = b; }
    __syncthreads();
    if (threadIdx.x == 0) {
        a = sa[0] + sa[1] + sa[2] + sa[3];
        b = sb[0] + sb[1] + sb[2] + sb[3];
    }
}

__global__ void k_zero(float* ws) {
    for (int i = threadIdx.x; i < OFF_GATE; i += 256) ws[i] = 0.f;
}

// per-channel sum/sumsq of x over (N,T,V). grid 2048 = 128c * 16 groups
__global__ __launch_bounds__(256) void k_bn1_stats(const float* __restrict__ x, float* __restrict__ ws) {
    int c = blockIdx.x & 127;
    int g = blockIdx.x >> 7;
    float s = 0.f, ss = 0.f;
    for (int nn = 0; nn < 4; ++nn) {
        int n = g * 4 + nn;
        const float4* row = (const float4*)(x + (size_t)(n * CC + c) * TV);
        for (int i = threadIdx.x; i < TV / 4; i += 256) {
            float4 u = row[i];
            s  += u.x + u.y + u.z + u.w;
            ss += u.x * u.x + u.y * u.y + u.z * u.z + u.w * u.w;
        }
    }
    block_reduce2(s, ss);
    if (threadIdx.x == 0) {
        atomicAdd(&ws[OFF_SUM1 + c], s);
        atomicAdd(&ws[OFF_SUMSQ1 + c], ss);
    }
}

__global__ void k_bn1_final(const float* __restrict__ g1, const float* __restrict__ b1, float* ws) {
    int c = threadIdx.x;
    if (c < CC) {
        const float inv = 1.f / (float)(NN * TV);
        float m = ws[OFF_SUM1 + c] * inv;
        float var = ws[OFF_SUMSQ1 + c] * inv - m * m;
        float rstd = rsqrtf(var + 1e-5f);
        float A = rstd * g1[c];
        ws[OFF_A1 + c] = A;
        ws[OFF_B1 + c] = b1[c] - m * A;
    }
}

// fused BN1-apply + temporal shift-in, producing yT[n][j][c] bf16 (chunk-swizzled),
// plus p[n,c] raw sums. grid (118 j-tiles, 64 n). LDS transpose tile [128 c][64 j].
__global__ __launch_bounds__(256) void k_shift_yT(const float* __restrict__ x,
                                                  const float* __restrict__ shift_in,
                                                  const float* __restrict__ ws,
                                                  float* __restrict__ pglob,
                                                  ushort* __restrict__ yT) {
    __shared__ ushort ytile[CC][64];
    __shared__ float psum[CC];
    int jt = blockIdx.x, n = blockIdx.y;
    int j0 = jt * 64;
    int tid = threadIdx.x;
    if (tid < CC) psum[tid] = 0.f;
    __syncthreads();
    int jq = tid & 7;        // j-chunk within tile
    int cb = tid >> 3;       // 0..31
    for (int ci = 0; ci < 4; ++ci) {
        int c = cb + 32 * ci;
        float sh = shift_in[c];
        float A = ws[OFF_A1 + c], B = ws[OFF_B1 + c];
        const float* row = x + (size_t)(n * CC + c) * TV;
        ushort pk[8];
        float s = 0.f;
#pragma unroll
        for (int e = 0; e < 8; ++e) {
            int j = j0 + jq * 8 + e;
            float yv = 0.f;
            if (j < TV) {
                int t = j / VV;
                int v = j - t * VV;
                float pos = (float)t + sh;
                float f0 = floorf(pos);
                int i0 = (int)f0;
                float frac = pos - f0;
                int i1 = i0 + 1;
                float w0 = (i0 >= 0 && i0 < TT) ? (1.f - frac) : 0.f;
                float w1 = (i1 >= 0 && i1 < TT) ? frac : 0.f;
                int i0c = min(max(i0, 0), TT - 1), i1c = min(max(i1, 0), TT - 1);
                float x0 = row[i0c * VV + v], x1 = row[i1c * VV + v];
                yv = (w0 * x0 + w1 * x1) * A + (w0 + w1) * B;
            }
            s += yv;
            pk[e] = f2bf(yv);
        }
        atomicAdd(&psum[c], s);
        uint32_t dw[4];
#pragma unroll
        for (int h = 0; h < 4; ++h) dw[h] = (uint32_t)pk[2 * h] | ((uint32_t)pk[2 * h + 1] << 16);
        *(uint4*)&ytile[c][jq * 8] = *(uint4*)dw;   // byte c*128 + jq*16, conflict-free b128
    }
    __syncthreads();
    // phase B: transposed read (lane=j -> banks spread by j/2, conflict-free), chunk-swizzled store
    int j = tid & 63;
    int w = tid >> 6;
    for (int it = 0; it < 4; ++it) {
        int s = w * 4 + it;          // c-chunk 0..15 (c = 8s..8s+7)
        uint32_t dw[4];
#pragma unroll
        for (int h = 0; h < 4; ++h) {
            ushort lo = ytile[8 * s + 2 * h][j];
            ushort hi = ytile[8 * s + 2 * h + 1][j];
            dw[h] = (uint32_t)lo | ((uint32_t)hi << 16);
        }
        size_t rowb = ((size_t)(n * JPAD + j0 + j)) * 128;   // elements
        *(uint4*)&yT[rowb + (size_t)((s ^ (j & 7)) << 3)] = *(uint4*)dw;
    }
    if (tid < CC) atomicAdd(&pglob[n * CC + tid], psum[tid]);
}

// fc1 -> relu -> fc2 -> softmax(logits/tao). one block.
__global__ void k_gate(const float* __restrict__ fc1_w, const float* __restrict__ fc1_b,
                       const float* __restrict__ fc2_w, const float* __restrict__ fc2_b,
                       const int* __restrict__ epoch_p, float* ws) {
    __shared__ float hsh[NN][RR];
    int n = threadIdx.x >> 2;
    int rq = threadIdx.x & 3;
    const float invTV = 1.f / (float)TV;
    for (int r = rq * 8; r < rq * 8 + 8; ++r) {
        float acc = 0.f;
        for (int c = 0; c < CC; ++c) acc += ws[OFF_P + n * CC + c] * fc1_w[r * CC + c];
        hsh[n][r] = fmaxf(acc * invTV + fc1_b[r], 0.f);
    }
    __syncthreads();
    if (threadIdx.x < NN) {
        int nn = threadIdx.x;
        int ep = *epoch_p;
        float tao = (ep < 60) ? (-(29.f / 60.f) * (float)ep + 30.f) : 1.f;
        float li[4];
        float mx = -1e30f;
        for (int k = 0; k < 4; ++k) {
            float acc = fc2_b[k];
            for (int r = 0; r < RR; ++r) acc += hsh[nn][r] * fc2_w[k * RR + r];
            li[k] = acc / tao;
            mx = fmaxf(mx, li[k]);
        }
        float se = 0.f;
        for (int k = 0; k < 4; ++k) { li[k] = expf(li[k] - mx); se += li[k]; }
        float inv = 1.f / se;
        for (int k = 0; k < 4; ++k) ws[OFF_GATE + nn * 4 + k] = li[k] * inv;
    }
}

// wT[n][d][c] bf16 (chunk-swizzled): w = sum_k gate[n,k]*tw[k,c,d]. grid 1024x256
__global__ __launch_bounds__(256) void k_wmixT(const float* __restrict__ tw, const float* __restrict__ ws,
                                               ushort* __restrict__ wT) {
    int idx = blockIdx.x * 256 + threadIdx.x;    // 64n * 16s * 256d
    int n = idx >> 12;
    int s = (idx >> 8) & 15;
    int d = idx & 255;
    const float* g = &ws[OFF_GATE + n * 4];
    float g0 = g[0], g1 = g[1], g2 = g[2], g3 = g[3];
    uint32_t dw[4];
#pragma unroll
    for (int h = 0; h < 4; ++h) {
        ushort e01[2];
#pragma unroll
        for (int q = 0; q < 2; ++q) {
            int c = s * 8 + 2 * h + q;
            const float* twc = tw + (size_t)c * DD + d;
            float wv = g0 * twc[0] + g1 * twc[32768] + g2 * twc[65536] + g3 * twc[98304];
            e01[q] = f2bf(wv);
        }
        dw[h] = (uint32_t)e01[0] | ((uint32_t)e01[1] << 16);
    }
    *(uint4*)&wT[((size_t)n * DD + d) * 128 + (size_t)((s ^ (d & 7)) << 3)] = *(uint4*)dw;
}

__global__ void k_bmix(const float* __restrict__ tb, float* __restrict__ ws) {
    int n = blockIdx.x, d = threadIdx.x;
    const float* g = &ws[OFF_GATE + n * 4];
    ws[OFF_BBUF + n * DD + d] = g[0] * tb[d] + g[1] * tb[DD + d] + g[2] * tb[2 * DD + d] + g[3] * tb[3 * DD + d];
}

// MFMA GEMM: z[n, d-tile 128, j-tile 128] = relu(wT . yT + b), K=C=128 staged once.
// 4 waves 2x2; per wave 4x4 16x16 tiles. grid (59, 2, 64).
__global__ __launch_bounds__(256) void k_gemm(const ushort* __restrict__ yT,
                                              const ushort* __restrict__ wT,
                                              const float* __restrict__ ws,
                                              ushort* __restrict__ zbuf) {
    __shared__ ushort wl[128 * 128];
    __shared__ ushort yl[128 * 128];
    int jt = blockIdx.x, dt = blockIdx.y, n = blockIdx.z;
    int tid = threadIdx.x;
    const char* wsrc = (const char*)(wT + ((size_t)n * DD + dt * 128) * 128);
    const char* ysrc = (const char*)(yT + ((size_t)n * JPAD + jt * 128) * 128);
#pragma unroll
    for (int i = 0; i < 8; ++i) {
        async_copy16(wsrc + (size_t)(i * 256 + tid) * 16, (char*)wl + (i * 256 + tid) * 16);
        async_copy16(ysrc + (size_t)(i * 256 + tid) * 16, (char*)yl + (i * 256 + tid) * 16);
    }
    __syncthreads();
    int lane = tid & 63;
    int wid = tid >> 6;
    int wm = wid >> 1, wn = wid & 1;
    int l16 = lane & 15, g = lane >> 4;
    f32x4 acc[4][4];
#pragma unroll
    for (int a = 0; a < 4; ++a)
#pragma unroll
        for (int b = 0; b < 4; ++b) acc[a][b] = (f32x4)0.f;
#pragma unroll
    for (int ks = 0; ks < 4; ++ks) {
        short8 af[4], bfr[4];
        int chunk = (ks * 4 + g) ^ (l16 & 7);
#pragma unroll
        for (int mi = 0; mi < 4; ++mi) {
            int r = wm * 64 + mi * 16 + l16;
            af[mi] = *(const short8*)&wl[r * 128 + chunk * 8];
        }
#pragma unroll
        for (int ni = 0; ni < 4; ++ni) {
            int r = wn * 64 + ni * 16 + l16;
            bfr[ni] = *(const short8*)&yl[r * 128 + chunk * 8];
        }
#pragma unroll
        for (int mi = 0; mi < 4; ++mi)
#pragma unroll
            for (int ni = 0; ni < 4; ++ni)
                acc[mi][ni] = __builtin_amdgcn_mfma_f32_16x16x32_bf16(af[mi], bfr[ni], acc[mi][ni], 0, 0, 0);
    }
#pragma unroll
    for (int mi = 0; mi < 4; ++mi) {
#pragma unroll
        for (int r = 0; r < 4; ++r) {
            int d = dt * 128 + wm * 64 + mi * 16 + g * 4 + r;
            float bias = ws[OFF_BBUF + n * DD + d];
            size_t zrow = ((size_t)n * DD + d) * TV;
#pragma unroll
            for (int ni = 0; ni < 4; ++ni) {
                int j = jt * 128 + wn * 64 + ni * 16 + l16;
                if (j < TV) {
                    float v = fmaxf(acc[mi][ni][r] + bias, 0.f);
                    zbuf[zrow + j] = f2bf(v);
                }
            }
        }
    }
}

// per-d sum/sumsq of shifted z. grid 4096 = 256d * 16 groups
__global__ __launch_bounds__(256) void k_bn2_stats(const ushort* __restrict__ zbuf,
                                                   const float* __restrict__ shift_out,
                                                   float* __restrict__ ws) {
    __shared__ float w0s[TT], w1s[TT];
    __shared__ int   i0s[TT], i1s[TT];
    int d = blockIdx.x & 255;
    int g = blockIdx.x >> 8;
    float sh = shift_out[d];
    for (int t = threadIdx.x; t < TT; t += 256) {
        float pos = (float)t + sh;
        float f0 = floorf(pos);
        int i0 = (int)f0;
        float frac = pos - f0;
        int i1 = i0 + 1;
        w0s[t] = (i0 >= 0 && i0 < TT) ? (1.f - frac) : 0.f;
        w1s[t] = (i1 >= 0 && i1 < TT) ? frac : 0.f;
        i0s[t] = min(max(i0, 0), TT - 1);
        i1s[t] = min(max(i1, 0), TT - 1);
    }
    __syncthreads();
    float s = 0.f, ss = 0.f;
    for (int nn = 0; nn < 4; ++nn) {
        int n = g * 4 + nn;
        const ushort* zrow = zbuf + (size_t)(n * DD + d) * TV;
        for (int j = threadIdx.x; j < TV; j += 256) {
            int t = j / VV, v = j - t * VV;
            float z0 = bf2f(zrow[i0s[t] * VV + v]);
            float z1 = bf2f(zrow[i1s[t] * VV + v]);
            float sv = w0s[t] * z0 + w1s[t] * z1;
            s += sv;
            ss += sv * sv;
        }
    }
    __syncthreads();
    block_reduce2(s, ss);
    if (threadIdx.x == 0) {
        atomicAdd(&ws[OFF_SUM2 + d], s);
        atomicAdd(&ws[OFF_SUMSQ2 + d], ss);
    }
}

__global__ void k_bn2_final(const float* __restrict__ g2, const float* __restrict__ b2, float* ws) {
    int d = threadIdx.x;
    if (d < DD) {
        const float inv = 1.f / (float)(NN * TV);
        float m = ws[OFF_SUM2 + d] * inv;
        float var = ws[OFF_SUMSQ2 + d] * inv - m * m;
        float rstd = rsqrtf(var + 1e-5f);
        float A = rstd * g2[d];
        ws[OFF_A2 + d] = A;
        ws[OFF_B2 + d] = b2[d] - m * A;
    }
}

// out = shifted(z)*A2 + B2, fp32. grid 16384 = n*256+d
__global__ __launch_bounds__(256) void k_out(const ushort* __restrict__ zbuf,
                                             const float* __restrict__ shift_out,
                                             const float* __restrict__ ws,
                                             float* __restrict__ out) {
    __shared__ float w0s[TT], w1s[TT];
    __shared__ int   i0s[TT], i1s[TT];
    int n = blockIdx.x >> 8, d = blockIdx.x & 255;
    float sh = shift_out[d];
    for (int t = threadIdx.x; t < TT; t += 256) {
        float pos = (float)t + sh;
        float f0 = floorf(pos);
        int i0 = (int)f0;
        float frac = pos - f0;
        int i1 = i0 + 1;
        w0s[t] = (i0 >= 0 && i0 < TT) ? (1.f - frac) : 0.f;
        w1s[t] = (i1 >= 0 && i1 < TT) ? frac : 0.f;
        i0s[t] = min(max(i0, 0), TT - 1);
        i1s[t] = min(max(i1, 0), TT - 1);
    }
    __syncthreads();
    float A = ws[OFF_A2 + d], B = ws[OFF_B2 + d];
    const ushort* zrow = zbuf + (size_t)(n * DD + d) * TV;
    float* orow = out + (size_t)(n * DD + d) * TV;
    for (int j = threadIdx.x; j < TV; j += 256) {
        int t = j / VV, v = j - t * VV;
        float z0 = bf2f(zrow[i0s[t] * VV + v]);
        float z1 = bf2f(zrow[i1s[t] * VV + v]);
        orow[j] = (w0s[t] * z0 + w1s[t] * z1) * A + B;
    }
}

extern "C" void kernel_launch(void* const* d_in, const int* in_sizes, int n_in,
                              void* d_out, int out_size, void* d_ws, size_t ws_size,
                              hipStream_t stream) {
    const float* x        = (const float*)d_in[0];
    const int*   epoch    = (const int*)d_in[1];
    const float* bn1_g    = (const float*)d_in[2];
    const float* bn1_b    = (const float*)d_in[3];
    const float* bn2_g    = (const float*)d_in[4];
    const float* bn2_b    = (const float*)d_in[5];
    const float* shift_in = (const float*)d_in[6];
    const float* shift_out= (const float*)d_in[7];
    const float* fc1_w    = (const float*)d_in[8];
    const float* fc1_b    = (const float*)d_in[9];
    const float* fc2_w    = (const float*)d_in[10];
    const float* fc2_b    = (const float*)d_in[11];
    const float* tw       = (const float*)d_in[12];
    const float* tb       = (const float*)d_in[13];
    float* out = (float*)d_out;
    float* ws  = (float*)d_ws;
    ushort* yT = (ushort*)d_out;                               // 123.7 MB bf16, consumed before k_out
    ushort* wT = (ushort*)((char*)d_ws + WT_BYTE_OFF);
    ushort* zb = (ushort*)((char*)d_ws + Z_BYTE_OFF);

    k_zero<<<1, 256, 0, stream>>>(ws);
    k_bn1_stats<<<2048, 256, 0, stream>>>(x, ws);
    k_bn1_final<<<1, 128, 0, stream>>>(bn1_g, bn1_b, ws);
    k_shift_yT<<<dim3(118, 64), 256, 0, stream>>>(x, shift_in, ws, ws + OFF_P, yT);
    k_gate<<<1, 256, 0, stream>>>(fc1_w, fc1_b, fc2_w, fc2_b, epoch, ws);
    k_wmixT<<<1024, 256, 0, stream>>>(tw, ws, wT);
    k_bmix<<<64, 256, 0, stream>>>(tb, ws);
    k_gemm<<<dim3(59, 2, NN), 256, 0, stream>>>(yT, wT, ws, zb);
    k_bn2_stats<<<4096, 256, 0, stream>>>(zb, shift_out, ws);
    k_bn2_final<<<1, 256, 0, stream>>>(bn2_g, bn2_b, ws);
    k_out<<<16384, 256, 0, stream>>>(zb, shift_out, ws, out);
}

// Round 3
// 599.848 us; speedup vs baseline: 2.0544x; 1.4012x over previous
//
#include <hip/hip_runtime.h>
#include <stdint.h>

#define NN 64
#define CC 128
#define TT 300
#define VV 25
#define TV 7500
#define DD 256
#define RR 32
#define JPAD 7552   // 59*128 padded j-rows (y) and padded z row stride

// ws float offsets
#define OFF_SUM1   0
#define OFF_SUMSQ1 128
#define OFF_A1     256
#define OFF_B1     384
#define OFF_SUM2   512
#define OFF_SUMSQ2 768
#define OFF_A2     1024
#define OFF_B2     1280
#define OFF_P      1536          // 64*128 raw sums
#define OFF_GATE   9728          // 64*4
#define OFF_BBUF   9984          // 64*256
#define FLOAT_REGION 26368
#define WT_BYTE_OFF ((size_t)FLOAT_REGION * 4)
#define WT_BYTES    ((size_t)NN * DD * CC * 2)          // 4 MB bf16 wT[n][d][c] chunk-swizzled
#define Z_BYTE_OFF  (WT_BYTE_OFF + WT_BYTES)            // z: 64*256*7552 bf16 = 247.5 MB

typedef __attribute__((ext_vector_type(8))) short short8;
typedef __attribute__((ext_vector_type(4))) float f32x4;

typedef const __attribute__((address_space(1))) uint32_t gas_u32;
typedef __attribute__((address_space(3))) uint32_t las_u32;

__device__ inline ushort f2bf(float f) {
    uint32_t u = __float_as_uint(f);
    u += 0x7fffu + ((u >> 16) & 1u);
    return (ushort)(u >> 16);
}
__device__ inline float bf2f(ushort v) { return __uint_as_float(((uint32_t)v) << 16); }
__device__ inline void async_copy16(const void* g, void* l) {
    __builtin_amdgcn_global_load_lds((gas_u32*)g, (las_u32*)l, 16, 0, 0);
}

__device__ inline void block_reduce2(float& a, float& b) {
    __shared__ float sa[4], sb[4];
    for (int off = 32; off > 0; off >>= 1) {
        a += __shfl_down(a, off);
        b += __shfl_down(b, off);
    }
    int lane = threadIdx.x & 63, wid = threadIdx.x >> 6;
    if (lane == 0) { sa[wid] = a; sb[wid] = b; }
    __syncthreads();
    if (threadIdx.x == 0) {
        a = sa[0] + sa[1] + sa[2] + sa[3];
        b = sb[0] + sb[1] + sb[2] + sb[3];
    }
}

__global__ void k_zero(float* ws) {
    for (int i = threadIdx.x; i < OFF_GATE; i += 256) ws[i] = 0.f;
}

__global__ __launch_bounds__(256) void k_bn1_stats(const float* __restrict__ x, float* __restrict__ ws) {
    int c = blockIdx.x & 127;
    int g = blockIdx.x >> 7;
    float s = 0.f, ss = 0.f;
    for (int nn = 0; nn < 4; ++nn) {
        int n = g * 4 + nn;
        const float4* row = (const float4*)(x + (size_t)(n * CC + c) * TV);
        for (int i = threadIdx.x; i < TV / 4; i += 256) {
            float4 u = row[i];
            s  += u.x + u.y + u.z + u.w;
            ss += u.x * u.x + u.y * u.y + u.z * u.z + u.w * u.w;
        }
    }
    block_reduce2(s, ss);
    if (threadIdx.x == 0) {
        atomicAdd(&ws[OFF_SUM1 + c], s);
        atomicAdd(&ws[OFF_SUMSQ1 + c], ss);
    }
}

__global__ void k_bn1_final(const float* __restrict__ g1, const float* __restrict__ b1, float* ws) {
    int c = threadIdx.x;
    if (c < CC) {
        const float inv = 1.f / (float)(NN * TV);
        float m = ws[OFF_SUM1 + c] * inv;
        float var = ws[OFF_SUMSQ1 + c] * inv - m * m;
        float rstd = rsqrtf(var + 1e-5f);
        float A = rstd * g1[c];
        ws[OFF_A1 + c] = A;
        ws[OFF_B1 + c] = b1[c] - m * A;
    }
}

// BN1-apply + shift-in -> yT[n][j][c] bf16 (chunk pos s^(j&7)), + p sums.
// grid (118 j-tiles of 64, 64 n). LDS tile [128c][64j], 2-key XOR swizzled.
__global__ __launch_bounds__(256) void k_shift_yT(const float* __restrict__ x,
                                                  const float* __restrict__ shift_in,
                                                  const float* __restrict__ ws,
                                                  float* __restrict__ pglob,
                                                  ushort* __restrict__ yT) {
    __shared__ ushort ytile[CC * 64];   // 16 KB; elem (c, jl) at c*64 + m(c,jl)*8 + (jl&7)
    int jt = blockIdx.x, n = blockIdx.y;
    int j0 = jt * 64;
    int tid = threadIdx.x;
    int jq = tid & 7;        // j chunk 0..7
    int cb = tid >> 3;       // 0..31
    for (int ci = 0; ci < 4; ++ci) {
        int c = cb + 32 * ci;
        float sh = shift_in[c];
        float A = ws[OFF_A1 + c], B = ws[OFF_B1 + c];
        const float* row = x + (size_t)(n * CC + c) * TV;
        ushort pk[8];
        float s = 0.f;
#pragma unroll
        for (int e = 0; e < 8; ++e) {
            int j = j0 + jq * 8 + e;
            float yv = 0.f;
            if (j < TV) {
                int t = j / VV;
                int v = j - t * VV;
                float pos = (float)t + sh;
                float f0 = floorf(pos);
                int i0 = (int)f0;
                float frac = pos - f0;
                int i1 = i0 + 1;
                float w0 = (i0 >= 0 && i0 < TT) ? (1.f - frac) : 0.f;
                float w1 = (i1 >= 0 && i1 < TT) ? frac : 0.f;
                int i0c = min(max(i0, 0), TT - 1), i1c = min(max(i1, 0), TT - 1);
                float x0 = row[i0c * VV + v], x1 = row[i1c * VV + v];
                yv = (w0 * x0 + w1 * x1) * A + (w0 + w1) * B;
            }
            s += yv;
            pk[e] = f2bf(yv);
        }
        // p reduction over the 8 jq-lanes (contiguous lanes share c)
        for (int off = 4; off > 0; off >>= 1) s += __shfl_down(s, off, 8);
        if (jq == 0) atomicAdd(&pglob[n * CC + c], s);
        uint32_t dw[4];
#pragma unroll
        for (int h = 0; h < 4; ++h) dw[h] = (uint32_t)pk[2 * h] | ((uint32_t)pk[2 * h + 1] << 16);
        int m = jq ^ (c & 7) ^ ((c >> 3) & 7);
        *(uint4*)&ytile[c * 64 + m * 8] = *(uint4*)dw;
    }
    __syncthreads();
    // phase B: build c-contiguous 16B chunks, coalesced row stores
    for (int it = 0; it < 4; ++it) {
        int jl = (tid >> 3) + 32 * (it & 1);       // 0..63
        int s  = (tid & 7) + 8 * (it >> 1);        // 0..15
        uint32_t dw[4];
#pragma unroll
        for (int h = 0; h < 4; ++h) {
            int c0 = 8 * s + 2 * h, c1 = c0 + 1;
            int m0 = (jl >> 3) ^ (c0 & 7) ^ (s & 7);
            int m1 = (jl >> 3) ^ (c1 & 7) ^ (s & 7);
            ushort lo = ytile[c0 * 64 + m0 * 8 + (jl & 7)];
            ushort hi = ytile[c1 * 64 + m1 * 8 + (jl & 7)];
            dw[h] = (uint32_t)lo | ((uint32_t)hi << 16);
        }
        int jg = j0 + jl;
        size_t rowb = ((size_t)n * JPAD + jg) * 128;
        *(uint4*)&yT[rowb + (size_t)((s ^ (jg & 7)) << 3)] = *(uint4*)dw;
    }
}

__global__ void k_gate(const float* __restrict__ fc1_w, const float* __restrict__ fc1_b,
                       const float* __restrict__ fc2_w, const float* __restrict__ fc2_b,
                       const int* __restrict__ epoch_p, float* ws) {
    __shared__ float hsh[NN][RR];
    int n = threadIdx.x >> 2;
    int rq = threadIdx.x & 3;
    const float invTV = 1.f / (float)TV;
    for (int r = rq * 8; r < rq * 8 + 8; ++r) {
        float acc = 0.f;
        for (int c = 0; c < CC; ++c) acc += ws[OFF_P + n * CC + c] * fc1_w[r * CC + c];
        hsh[n][r] = fmaxf(acc * invTV + fc1_b[r], 0.f);
    }
    __syncthreads();
    if (threadIdx.x < NN) {
        int nn = threadIdx.x;
        int ep = *epoch_p;
        float tao = (ep < 60) ? (-(29.f / 60.f) * (float)ep + 30.f) : 1.f;
        float li[4];
        float mx = -1e30f;
        for (int k = 0; k < 4; ++k) {
            float acc = fc2_b[k];
            for (int r = 0; r < RR; ++r) acc += hsh[nn][r] * fc2_w[k * RR + r];
            li[k] = acc / tao;
            mx = fmaxf(mx, li[k]);
        }
        float se = 0.f;
        for (int k = 0; k < 4; ++k) { li[k] = expf(li[k] - mx); se += li[k]; }
        float inv = 1.f / se;
        for (int k = 0; k < 4; ++k) ws[OFF_GATE + nn * 4 + k] = li[k] * inv;
    }
}

// wT[n][d][c] bf16 chunk-swizzled. lanes: s fastest -> row-contiguous stores.
__global__ __launch_bounds__(256) void k_wmixT(const float* __restrict__ tw, const float* __restrict__ ws,
                                               ushort* __restrict__ wT) {
    int idx = blockIdx.x * 256 + threadIdx.x;
    int n = idx >> 12;
    int d = (idx >> 4) & 255;
    int s = idx & 15;
    const float* g = &ws[OFF_GATE + n * 4];
    float g0 = g[0], g1 = g[1], g2 = g[2], g3 = g[3];
    uint32_t dw[4];
#pragma unroll
    for (int h = 0; h < 4; ++h) {
        ushort e01[2];
#pragma unroll
        for (int q = 0; q < 2; ++q) {
            int c = s * 8 + 2 * h + q;
            const float* twc = tw + (size_t)c * DD + d;
            float wv = g0 * twc[0] + g1 * twc[32768] + g2 * twc[65536] + g3 * twc[98304];
            e01[q] = f2bf(wv);
        }
        dw[h] = (uint32_t)e01[0] | ((uint32_t)e01[1] << 16);
    }
    *(uint4*)&wT[((size_t)n * DD + d) * 128 + (size_t)((s ^ (d & 7)) << 3)] = *(uint4*)dw;
}

__global__ void k_bmix(const float* __restrict__ tb, float* __restrict__ ws) {
    int n = blockIdx.x, d = threadIdx.x;
    const float* g = &ws[OFF_GATE + n * 4];
    ws[OFF_BBUF + n * DD + d] = g[0] * tb[d] + g[1] * tb[DD + d] + g[2] * tb[2 * DD + d] + g[3] * tb[3 * DD + d];
}

// MFMA GEMM: per (jt, n) stage y once; dt=0,1 inner loop re-stages w half.
__global__ __launch_bounds__(256) void k_gemm(const ushort* __restrict__ yT,
                                              const ushort* __restrict__ wT,
                                              const float* __restrict__ ws,
                                              ushort* __restrict__ zbuf) {
    __shared__ ushort yl[128 * 128];
    __shared__ ushort wl[128 * 128];
    int jt = blockIdx.x, n = blockIdx.y;
    int tid = threadIdx.x;
    const char* ysrc = (const char*)(yT + ((size_t)n * JPAD + jt * 128) * 128);
#pragma unroll
    for (int i = 0; i < 8; ++i)
        async_copy16(ysrc + (size_t)(i * 256 + tid) * 16, (char*)yl + (i * 256 + tid) * 16);
    int lane = tid & 63;
    int wid = tid >> 6;
    int wm = wid >> 1, wn = wid & 1;
    int l16 = lane & 15, g = lane >> 4;
    for (int dt = 0; dt < 2; ++dt) {
        const char* wsrc = (const char*)(wT + ((size_t)n * DD + dt * 128) * 128);
        if (dt) __syncthreads();   // waves done reading wl from dt=0
#pragma unroll
        for (int i = 0; i < 8; ++i)
            async_copy16(wsrc + (size_t)(i * 256 + tid) * 16, (char*)wl + (i * 256 + tid) * 16);
        __syncthreads();
        f32x4 acc[4][4];
#pragma unroll
        for (int a = 0; a < 4; ++a)
#pragma unroll
            for (int b = 0; b < 4; ++b) acc[a][b] = (f32x4)0.f;
#pragma unroll
        for (int ks = 0; ks < 4; ++ks) {
            short8 af[4], bfr[4];
            int chunk = (ks * 4 + g) ^ (l16 & 7);
#pragma unroll
            for (int mi = 0; mi < 4; ++mi)
                af[mi] = *(const short8*)&wl[(wm * 64 + mi * 16 + l16) * 128 + chunk * 8];
#pragma unroll
            for (int ni = 0; ni < 4; ++ni)
                bfr[ni] = *(const short8*)&yl[(wn * 64 + ni * 16 + l16) * 128 + chunk * 8];
#pragma unroll
            for (int mi = 0; mi < 4; ++mi)
#pragma unroll
                for (int ni = 0; ni < 4; ++ni)
                    acc[mi][ni] = __builtin_amdgcn_mfma_f32_16x16x32_bf16(af[mi], bfr[ni], acc[mi][ni], 0, 0, 0);
        }
#pragma unroll
        for (int mi = 0; mi < 4; ++mi) {
#pragma unroll
            for (int r = 0; r < 4; ++r) {
                int d = dt * 128 + wm * 64 + mi * 16 + g * 4 + r;
                float bias = ws[OFF_BBUF + n * DD + d];
                size_t zrow = ((size_t)n * DD + d) * JPAD + jt * 128;
#pragma unroll
                for (int ni = 0; ni < 4; ++ni) {
                    int j = wn * 64 + ni * 16 + l16;
                    zbuf[zrow + j] = f2bf(fmaxf(acc[mi][ni][r] + bias, 0.f));
                }
            }
        }
    }
}

// streaming BN2 stats: stage z row in LDS, 2-tap shifted combine, reduce.
__global__ __launch_bounds__(256) void k_bn2_stats(const ushort* __restrict__ zbuf,
                                                   const float* __restrict__ shift_out,
                                                   float* __restrict__ ws) {
    __shared__ ushort zl[JPAD];   // 15104 B
    int d = blockIdx.x & 255;
    int n = blockIdx.x >> 8;
    int tid = threadIdx.x;
    const char* zrow = (const char*)(zbuf + ((size_t)n * DD + d) * JPAD);
    for (int k = tid; k < JPAD / 8; k += 256)
        async_copy16(zrow + (size_t)k * 16, (char*)zl + k * 16);
    __syncthreads();
    float sh = shift_out[d];
    float alpha = (sh >= 0.f) ? (1.f - sh) : (-sh);
    float beta  = (sh >= 0.f) ? sh : (1.f + sh);
    int o25 = (sh >= 0.f) ? 0 : -25;
    float s = 0.f, ss = 0.f;
    for (int jj = tid; jj < TV; jj += 256) {
        int i0 = jj + o25, i1 = jj + o25 + 25;
        float z0 = bf2f(zl[max(i0, 0)]);
        float z1 = bf2f(zl[min(i1, TV - 1)]);
        z0 = (i0 >= 0) ? z0 : 0.f;
        z1 = (i1 < TV) ? z1 : 0.f;
        float zs = alpha * z0 + beta * z1;
        s += zs;
        ss += zs * zs;
    }
    block_reduce2(s, ss);
    if (tid == 0) {
        atomicAdd(&ws[OFF_SUM2 + d], s);
        atomicAdd(&ws[OFF_SUMSQ2 + d], ss);
    }
}

__global__ void k_bn2_final(const float* __restrict__ g2, const float* __restrict__ b2, float* ws) {
    int d = threadIdx.x;
    if (d < DD) {
        const float inv = 1.f / (float)(NN * TV);
        float m = ws[OFF_SUM2 + d] * inv;
        float var = ws[OFF_SUMSQ2 + d] * inv - m * m;
        float rstd = rsqrtf(var + 1e-5f);
        float A = rstd * g2[d];
        ws[OFF_A2 + d] = A;
        ws[OFF_B2 + d] = b2[d] - m * A;
    }
}

// out = shifted(z)*A2 + B2, float4 stores. grid 16384 = n*256+d
__global__ __launch_bounds__(256) void k_out(const ushort* __restrict__ zbuf,
                                             const float* __restrict__ shift_out,
                                             const float* __restrict__ ws,
                                             float* __restrict__ out) {
    __shared__ ushort zl[JPAD];
    int d = blockIdx.x & 255;
    int n = blockIdx.x >> 8;
    int tid = threadIdx.x;
    const char* zrow = (const char*)(zbuf + ((size_t)n * DD + d) * JPAD);
    for (int k = tid; k < JPAD / 8; k += 256)
        async_copy16(zrow + (size_t)k * 16, (char*)zl + k * 16);
    __syncthreads();
    float sh = shift_out[d];
    float alpha = (sh >= 0.f) ? (1.f - sh) : (-sh);
    float beta  = (sh >= 0.f) ? sh : (1.f + sh);
    int o25 = (sh >= 0.f) ? 0 : -25;
    float A = ws[OFF_A2 + d], B = ws[OFF_B2 + d];
    float4* orow = (float4*)(out + ((size_t)n * DD + d) * TV);
    for (int k = tid; k < TV / 4; k += 256) {
        int jj = k * 4;
        float4 o4;
        float* op = &o4.x;
#pragma unroll
        for (int q = 0; q < 4; ++q) {
            int i0 = jj + q + o25, i1 = jj + q + o25 + 25;
            float z0 = bf2f(zl[max(i0, 0)]);
            float z1 = bf2f(zl[min(i1, TV - 1)]);
            z0 = (i0 >= 0) ? z0 : 0.f;
            z1 = (i1 < TV) ? z1 : 0.f;
            op[q] = (alpha * z0 + beta * z1) * A + B;
        }
        orow[k] = o4;
    }
}

extern "C" void kernel_launch(void* const* d_in, const int* in_sizes, int n_in,
                              void* d_out, int out_size, void* d_ws, size_t ws_size,
                              hipStream_t stream) {
    const float* x        = (const float*)d_in[0];
    const int*   epoch    = (const int*)d_in[1];
    const float* bn1_g    = (const float*)d_in[2];
    const float* bn1_b    = (const float*)d_in[3];
    const float* bn2_g    = (const float*)d_in[4];
    const float* bn2_b    = (const float*)d_in[5];
    const float* shift_in = (const float*)d_in[6];
    const float* shift_out= (const float*)d_in[7];
    const float* fc1_w    = (const float*)d_in[8];
    const float* fc1_b    = (const float*)d_in[9];
    const float* fc2_w    = (const float*)d_in[10];
    const float* fc2_b    = (const float*)d_in[11];
    const float* tw       = (const float*)d_in[12];
    const float* tb       = (const float*)d_in[13];
    float* out = (float*)d_out;
    float* ws  = (float*)d_ws;
    ushort* yT = (ushort*)d_out;                    // parked in d_out until k_out
    ushort* wT = (ushort*)((char*)d_ws + WT_BYTE_OFF);
    ushort* zb = (ushort*)((char*)d_ws + Z_BYTE_OFF);

    k_zero<<<1, 256, 0, stream>>>(ws);
    k_bn1_stats<<<2048, 256, 0, stream>>>(x, ws);
    k_bn1_final<<<1, 128, 0, stream>>>(bn1_g, bn1_b, ws);
    k_shift_yT<<<dim3(118, 64), 256, 0, stream>>>(x, shift_in, ws, ws + OFF_P, yT);
    k_gate<<<1, 256, 0, stream>>>(fc1_w, fc1_b, fc2_w, fc2_b, epoch, ws);
    k_wmixT<<<1024, 256, 0, stream>>>(tw, ws, wT);
    k_bmix<<<64, 256, 0, stream>>>(tb, ws);
    k_gemm<<<dim3(59, 64), 256, 0, stream>>>(yT, wT, ws, zb);
    k_bn2_stats<<<16384, 256, 0, stream>>>(zb, shift_out, ws);
    k_bn2_final<<<1, 256, 0, stream>>>(bn2_g, bn2_b, ws);
    k_out<<<16384, 256, 0, stream>>>(zb, shift_out, ws, out);
}